// Round 2
// 423.860 us; speedup vs baseline: 1.0190x; 1.0190x over previous
//
#include <hip/hip_runtime.h>

#define B_ 2
#define N_ 131072
#define K_ 20
#define E_ 256
#define TEMP_ 0.05f
#define SCORE_THR_ 0.04f

// ws layout (float offsets):
//   [0,40)              score[B][K]   (final mean scores, written by kC)
//   [1024,11264)        xn [B][K][E]
//   [16384,26624)       sn [B][K][E]
//   [32768,+B*K*N)      mask [B][K][N]            (ends at 5275648)
//   [6291456,+1024*20)  score partials per kB block
#define WS_SCORE 0
#define WS_XN    1024
#define WS_SN    16384
#define WS_MASK  32768
#define WS_SPART 6291456

typedef __attribute__((ext_vector_type(8))) short short8;   // 8 bf16 (4 VGPRs)
typedef __attribute__((ext_vector_type(4))) float f32x4;    // MFMA C/D frag

__device__ inline float wave_sum(float v) {
    #pragma unroll
    for (int off = 32; off; off >>= 1) v += __shfl_xor(v, off, 64);
    return v;
}

// split f32 -> bf16 hi + bf16 lo (RTNE both), 8 elems from two float4
__device__ inline void cvt_hilo(const float4 a, const float4 b, short8& h, short8& l) {
    float f[8] = {a.x, a.y, a.z, a.w, b.x, b.y, b.z, b.w};
    #pragma unroll
    for (int j = 0; j < 8; ++j) {
        const unsigned u  = __float_as_uint(f[j]);
        const unsigned hb = (u + 0x7fffu + ((u >> 16) & 1u)) & 0xffff0000u;
        h[j] = (short)(hb >> 16);
        const float r = f[j] - __uint_as_float(hb);
        const unsigned v = __float_as_uint(r);
        l[j] = (short)((v + 0x7fffu + ((v >> 16) & 1u)) >> 16);
    }
}

// ---------------- Kernel A1: GEMM1 + GroupNorm + ReLU ----------------
__global__ __launch_bounds__(256) void kA1(const float* __restrict__ slots,
                                           const float* __restrict__ w1,
                                           const float* __restrict__ b1,
                                           const float* __restrict__ gn_g,
                                           const float* __restrict__ gn_b,
                                           float* __restrict__ ws) {
    __shared__ __align__(16) float slds[20 * 260];
    __shared__ float red[2];
    const int t = threadIdx.x;
    const int b = blockIdx.x >> 2, g = blockIdx.x & 3;
    if (t < 2) red[t] = 0.f;
    const float* sb = slots + (size_t)b * K_ * E_;
    #pragma unroll
    for (int i = 0; i < 20; ++i) slds[i * 260 + t] = sb[i * 256 + t];
    __syncthreads();

    const int c = t >> 2, q = t & 3;
    const int o = g * 64 + c;
    const float* w1r = w1 + (size_t)o * E_;
    float acc[5] = {0.f, 0.f, 0.f, 0.f, 0.f};
    for (int e4 = 0; e4 < 64; ++e4) {
        const float4 w4 = *(const float4*)(w1r + e4 * 4);
        #pragma unroll
        for (int kk = 0; kk < 5; ++kk) {
            const float4 s4 = *(const float4*)&slds[(q * 5 + kk) * 260 + e4 * 4];
            acc[kk] += w4.x * s4.x + w4.y * s4.y + w4.z * s4.z + w4.w * s4.w;
        }
    }
    const float bias = b1[o];
    float s1 = 0.f, s2 = 0.f;
    #pragma unroll
    for (int kk = 0; kk < 5; ++kk) {
        acc[kk] += bias;
        s1 += acc[kk];
        s2 += acc[kk] * acc[kk];
    }
    s1 = wave_sum(s1);
    s2 = wave_sum(s2);
    if ((t & 63) == 0) { atomicAdd(&red[0], s1); atomicAdd(&red[1], s2); }
    __syncthreads();
    const float mean = red[0] * (1.f / 1280.f);
    const float var  = red[1] * (1.f / 1280.f) - mean * mean;
    const float rstd = rsqrtf(var + 1e-5f);
    const float gg = gn_g[o], gb = gn_b[o];
    float* xn = ws + WS_XN + (size_t)b * K_ * E_;
    #pragma unroll
    for (int kk = 0; kk < 5; ++kk) {
        float v = (acc[kk] - mean) * rstd * gg + gb;
        v = v > 0.f ? v : 0.f;
        xn[(q * 5 + kk) * 256 + o] = v;
    }
}

// ---------------- Kernel A2: GEMM2 + bias + L2-normalize over E ----------------
__global__ __launch_bounds__(256) void kA2(const float* __restrict__ w2,
                                           const float* __restrict__ b2,
                                           float* __restrict__ ws) {
    __shared__ __align__(16) float xv[256];
    __shared__ float wred[4];
    const int t = threadIdx.x;
    const int b = blockIdx.x / 20, k = blockIdx.x % 20;
    const float* xn = ws + WS_XN + (size_t)(b * 20 + k) * 256;
    xv[t] = xn[t];
    __syncthreads();
    const float* w2r = w2 + (size_t)t * 256;
    float acc = 0.f;
    for (int e4 = 0; e4 < 64; ++e4) {
        const float4 w4 = *(const float4*)(w2r + e4 * 4);
        const float4 x4 = *(const float4*)&xv[e4 * 4];
        acc += w4.x * x4.x + w4.y * x4.y + w4.z * x4.z + w4.w * x4.w;
    }
    acc += b2[t];
    float sq = wave_sum(acc * acc);
    if ((t & 63) == 0) wred[t >> 6] = sq;
    __syncthreads();
    const float nsq = wred[0] + wred[1] + wred[2] + wred[3];
    const float inv = 1.f / fmaxf(sqrtf(nsq), 1e-12f);
    ws[WS_SN + (size_t)(b * 20 + k) * 256 + t] = acc * inv;
}

// ---------------- Kernel B v3: MFMA bf16 hi/lo logits + in-register softmax ----
// grid 1024 (512 blocks/batch, 256 points/block); 256 threads = 4 waves.
// Per wave-tile: 16 points x 32 slots (20 valid) via mfma_f32_16x16x32_bf16,
// 3 passes (fh*sh + fh*sl + fl*sh) x 8 ksteps x 2 slot N-tiles = 48 MFMA.
// Features: global->reg directly in A-frag order (lane = point lane&15,
// dims 8*(lane>>4)+j) — every 128B line fully consumed, no staging barrier.
// Slots: converted once/block into frag-layout bf16 hi/lo in 32 KB LDS.
__global__ __launch_bounds__(256, 2) void kB(const float* __restrict__ feat,
                                             float* __restrict__ ws) {
    __shared__ short8 sfh[2][8][64];   // [tile][kstep][lane] 16 KB
    __shared__ short8 sfl[2][8][64];   // 16 KB
    __shared__ float wsum[4][20];
    const int t = threadIdx.x;
    const int lane = t & 63, w = t >> 6;
    const int b = blockIdx.x >> 9, blk = blockIdx.x & 511;
    const int s = lane & 15, g = lane >> 4;

    // ---- prologue: build slot B-fragments (bf16 hi/lo) in LDS ----
    {
        #pragma unroll
        for (int i = 0; i < 4; ++i) {
            const int combo = w * 4 + i;          // 16 (tile,kstep) combos
            const int tile = combo >> 3, ks = combo & 7;
            const int slot = tile * 16 + s;
            short8 h, l;
            if (slot < K_) {
                const float* snp = ws + WS_SN + ((size_t)(b * K_ + slot)) * E_
                                 + ks * 32 + g * 8;
                cvt_hilo(*(const float4*)snp, *(const float4*)(snp + 4), h, l);
            } else {
                #pragma unroll
                for (int j = 0; j < 8; ++j) { h[j] = 0; l[j] = 0; }
            }
            sfh[tile][ks][lane] = h;
            sfl[tile][ks][lane] = l;
        }
    }
    __syncthreads();

    const float* fp0 = feat + ((size_t)b * N_ + blk * 256 + s) * E_;
    float sreg0 = 0.f, sreg1 = 0.f;

    for (int it = 0; it < 4; ++it) {
        const int pb = w * 64 + it * 16;          // within-block point base
        const float* fp = fp0 + (size_t)pb * E_;
        f32x4 c0 = {0.f, 0.f, 0.f, 0.f};
        f32x4 c1 = {0.f, 0.f, 0.f, 0.f};
        float nr = 0.f;
        #pragma unroll
        for (int ks = 0; ks < 8; ++ks) {
            const float* q = fp + ks * 32 + g * 8;
            const float4 a  = *(const float4*)q;
            const float4 bb = *(const float4*)(q + 4);
            nr += a.x * a.x + a.y * a.y + a.z * a.z + a.w * a.w
                + bb.x * bb.x + bb.y * bb.y + bb.z * bb.z + bb.w * bb.w;
            short8 fh, fl;
            cvt_hilo(a, bb, fh, fl);
            const short8 sh0 = sfh[0][ks][lane], sl0 = sfl[0][ks][lane];
            const short8 sh1 = sfh[1][ks][lane], sl1 = sfl[1][ks][lane];
            c0 = __builtin_amdgcn_mfma_f32_16x16x32_bf16(fh, sh0, c0, 0, 0, 0);
            c1 = __builtin_amdgcn_mfma_f32_16x16x32_bf16(fh, sh1, c1, 0, 0, 0);
            c0 = __builtin_amdgcn_mfma_f32_16x16x32_bf16(fh, sl0, c0, 0, 0, 0);
            c1 = __builtin_amdgcn_mfma_f32_16x16x32_bf16(fh, sl1, c1, 0, 0, 0);
            c0 = __builtin_amdgcn_mfma_f32_16x16x32_bf16(fl, sh0, c0, 0, 0, 0);
            c1 = __builtin_amdgcn_mfma_f32_16x16x32_bf16(fl, sh1, c1, 0, 0, 0);
        }
        // ||f||^2 for point pb+s: sum partials across the 4 lane-groups
        nr += __shfl_xor(nr, 16, 64);
        nr += __shfl_xor(nr, 32, 64);
        const float scl = rsqrtf(fmaxf(nr, 1e-24f)) * (1.f / TEMP_);

        // C layout: lane holds slot col = s (tile0) / 16+s (tile1),
        // point rows pb + 4*g + r.  Softmax per point = reduce over s lanes.
        float p0[4], p1[4];
        #pragma unroll
        for (int r = 0; r < 4; ++r) {
            const float sr = __shfl(scl, 4 * g + r, 64);   // scale of point 4g+r
            const float x0 = c0[r] * sr;
            const float x1 = c1[r] * sr;                   // valid only s<4
            float m = (s < 4) ? fmaxf(x0, x1) : x0;
            #pragma unroll
            for (int off = 1; off < 16; off <<= 1) m = fmaxf(m, __shfl_xor(m, off, 64));
            const float e0 = __expf(x0 - m);
            const float e1 = (s < 4) ? __expf(x1 - m) : 0.f;
            float su = e0 + e1;
            #pragma unroll
            for (int off = 1; off < 16; off <<= 1) su += __shfl_xor(su, off, 64);
            const float inv = 1.f / su;
            p0[r] = e0 * inv;
            p1[r] = e1 * inv;
        }
        const int col = blk * 256 + pb + 4 * g;
        float* mrow = ws + WS_MASK + ((size_t)b * K_ + s) * N_ + col;
        *(float4*)mrow = make_float4(p0[0], p0[1], p0[2], p0[3]);
        sreg0 += p0[0] + p0[1] + p0[2] + p0[3];
        if (s < 4) {
            float* mrow1 = ws + WS_MASK + ((size_t)b * K_ + 16 + s) * N_ + col;
            *(float4*)mrow1 = make_float4(p1[0], p1[1], p1[2], p1[3]);
            sreg1 += p1[0] + p1[1] + p1[2] + p1[3];
        }
    }

    // per-block score partials: sum over the wave's 64 points, then 4 waves
    sreg0 += __shfl_xor(sreg0, 16, 64);
    sreg0 += __shfl_xor(sreg0, 32, 64);
    sreg1 += __shfl_xor(sreg1, 16, 64);
    sreg1 += __shfl_xor(sreg1, 32, 64);
    if (lane < 16) wsum[w][lane] = sreg0;
    if (lane < 4)  wsum[w][16 + lane] = sreg1;
    __syncthreads();
    if (t < 20)
        ws[WS_SPART + (size_t)blockIdx.x * 20 + t] =
            wsum[0][t] + wsum[1][t] + wsum[2][t] + wsum[3][t];
}

// ---------------- Kernel C: reduce score partials ----------------
// grid 40 = (b,k); 64 threads
__global__ __launch_bounds__(64) void kC(float* __restrict__ ws) {
    const int l = threadIdx.x;
    const int b = blockIdx.x / 20, k = blockIdx.x % 20;
    const float* sp = ws + WS_SPART;
    float sum = 0.f;
    #pragma unroll
    for (int i = 0; i < 8; ++i)
        sum += sp[(size_t)(b * 512 + l + i * 64) * 20 + k];
    sum = wave_sum(sum);
    if (l == 0) ws[WS_SCORE + blockIdx.x] = sum * (1.f / (float)N_);
}

// ---------------- Kernel D: rank/filter + gather + renormalize ----------------
__global__ __launch_bounds__(256) void kD(const float* __restrict__ ws,
                                          float* __restrict__ out) {
    __shared__ float sc[20];
    __shared__ int rnk[20];
    __shared__ int src[20];
    __shared__ int nk_s;
    const int t = threadIdx.x;
    const int b = blockIdx.x >> 9;
    const int n = (blockIdx.x & 511) * 256 + t;
    if (t < 20) sc[t] = ws[WS_SCORE + b * 20 + t];
    if (t == 0) nk_s = 0;
    __syncthreads();
    if (t < 20) {
        const float mys = sc[t];
        int rank = 0;
        for (int j = 0; j < 20; ++j) {
            const float o = sc[j];
            rank += (o > mys) || (o == mys && j < t);
        }
        rnk[t] = rank;
    }
    __syncthreads();
    if (t < 20 && sc[t] >= SCORE_THR_) {
        int pos = 0;
        for (int j = 0; j < 20; ++j)
            pos += (sc[j] >= SCORE_THR_) && (rnk[j] < rnk[t]);
        src[pos] = t;
        atomicAdd(&nk_s, 1);
    }
    __syncthreads();
    const int nk = nk_s;
    const float* mg = ws + WS_MASK + (size_t)b * 20 * N_;
    float mv[20];
    float den = 1e-8f;
    #pragma unroll
    for (int p = 0; p < 20; ++p) {
        float v = 0.f;
        if (p < nk) v = mg[(size_t)src[p] * N_ + n];
        mv[p] = v;
        den += v;
    }
    const float r = 1.f / den;
    float* og = out + (size_t)b * 20 * N_ + n;
    #pragma unroll
    for (int p = 0; p < 20; ++p) og[(size_t)p * N_] = (p < nk) ? mv[p] * r : 0.f;
}

extern "C" void kernel_launch(void* const* d_in, const int* in_sizes, int n_in,
                              void* d_out, int out_size, void* d_ws, size_t ws_size,
                              hipStream_t stream) {
    const float* feat  = (const float*)d_in[0];
    const float* slots = (const float*)d_in[1];
    const float* w1    = (const float*)d_in[2];
    const float* b1    = (const float*)d_in[3];
    const float* gng   = (const float*)d_in[4];
    const float* gnb   = (const float*)d_in[5];
    const float* w2    = (const float*)d_in[6];
    const float* b2    = (const float*)d_in[7];
    float* ws  = (float*)d_ws;
    float* out = (float*)d_out;

    kA1<<<8,    256, 0, stream>>>(slots, w1, b1, gng, gnb, ws);
    kA2<<<40,   256, 0, stream>>>(w2, b2, ws);
    kB <<<1024, 256, 0, stream>>>(feat, ws);
    kC <<<40,   64,  0, stream>>>(ws);
    kD <<<1024, 256, 0, stream>>>(ws, out);
}